// Round 1
// baseline (2096.472 us; speedup 1.0000x reference)
//
#include <hip/hip_runtime.h>
#include <cstdint>

// SpacetimeNonLocalBlock: B=4, C=256, T=8, H=28, W=28 -> N=6272, IC=128.
// z = Wz @ softmax(theta(x)^T phi(x)) @ g(x)^T + x, all 1x1x1 convs = channel GEMMs.
// Round 0: fp32 baseline, flash-attention structure (no N*N materialization).
// Workspace layout (fp32): Q[B][N][IC] | K[B][N][IC] | V[B][N][IC] | Y[B][N][IC]
//   = 4 * 4*6272*128 * 4 B = 51.4 MB of d_ws.

#define BB   4
#define CCH  256
#define NPOS 6272
#define ICH  128
#define BNIC ((size_t)BB * NPOS * ICH)

// ---------------------------------------------------------------------------
// Kernel 1: projections. Out[b][n][o] = sum_c W[o][c] * x[b][c][n]
// grid (N/64, 384/64, B); block 256. which: 0=theta->Q, 1=phi->K, 2=g->V.
// ---------------------------------------------------------------------------
__global__ __launch_bounds__(256, 2)
void proj_kernel(const float* __restrict__ x,
                 const float* __restrict__ Wtheta,
                 const float* __restrict__ Wphi,
                 const float* __restrict__ Wg,
                 float* __restrict__ ws) {
  const int n0 = blockIdx.x * 64;
  const int og = blockIdx.y * 64;           // 0..383 in steps of 64
  const int b  = blockIdx.z;
  const int which   = og >> 7;              // 0,0,1,1,2,2
  const int o_local = og & 127;             // 0 or 64
  const float* W = (which == 0) ? Wtheta : ((which == 1) ? Wphi : Wg);
  float* Out = ws + (size_t)which * BNIC;

  __shared__ float Xt[64][17];              // [n][kk], +1 pad
  __shared__ float Wt[64][17];              // [o][kk], +1 pad

  const int tid = threadIdx.x;
  const int tx = tid & 15, ty = tid >> 4;
  float acc[4][4] = {};                     // rows n = ty*4+i, cols o = tx*4+j

  for (int c0 = 0; c0 < CCH; c0 += 16) {
    {
      const int nn = tid & 63;
      const int k4 = tid >> 6;              // 0..3
      #pragma unroll
      for (int p = 0; p < 4; ++p) {
        const int kk = k4 + p * 4;
        Xt[nn][kk] = x[((size_t)(b * CCH + c0 + kk)) * NPOS + n0 + nn];
      }
      const int wk = tid & 15;
      const int wo = tid >> 4;
      #pragma unroll
      for (int p = 0; p < 4; ++p) {
        const int oo = wo + p * 16;
        Wt[oo][wk] = W[(size_t)(o_local + oo) * CCH + c0 + wk];
      }
    }
    __syncthreads();
    #pragma unroll
    for (int kk = 0; kk < 16; ++kk) {
      float a_[4], b_[4];
      #pragma unroll
      for (int i = 0; i < 4; ++i) a_[i] = Xt[ty * 4 + i][kk];
      #pragma unroll
      for (int j = 0; j < 4; ++j) b_[j] = Wt[tx * 4 + j][kk];
      #pragma unroll
      for (int i = 0; i < 4; ++i)
        #pragma unroll
        for (int j = 0; j < 4; ++j) acc[i][j] += a_[i] * b_[j];
    }
    __syncthreads();
  }
  #pragma unroll
  for (int i = 0; i < 4; ++i) {
    float4 v;
    v.x = acc[i][0]; v.y = acc[i][1]; v.z = acc[i][2]; v.w = acc[i][3];
    *(float4*)&Out[((size_t)b * NPOS + n0 + ty * 4 + i) * ICH + o_local + tx * 4] = v;
  }
}

// ---------------------------------------------------------------------------
// Kernel 2: flash attention. Y[b][n][ic] = softmax_m(Q[n].K[m]) @ V[m][ic]
// grid (N/64, B); block 256. TQ=64, TK=32.
// LDS: Qs 32KB (XOR-swizzled quads) + KVs 16.5KB (K swizzled / V padded 132)
//      + Ps 4.5KB (bf16, stride 36) = 53KB -> 3 blocks/CU.
// ---------------------------------------------------------------------------
__device__ __forceinline__ int swz(int row, int qd) {
  return (row << 5) + (qd ^ ((row >> 2) & 7));   // quad-granular offset
}
__device__ __forceinline__ unsigned short f2bf(float f) {
  unsigned int u = __float_as_uint(f);
  u += 0x7fffu + ((u >> 16) & 1u);               // RNE
  return (unsigned short)(u >> 16);
}

#define TQ 64
#define TK 32

__global__ __launch_bounds__(256, 3)
void flash_kernel(const float* __restrict__ ws, float* __restrict__ Y) {
  const float* Q = ws;
  const float* K = ws + BNIC;
  const float* V = ws + 2 * BNIC;
  const int n0  = blockIdx.x * TQ;
  const int b   = blockIdx.y;
  const int tid = threadIdx.x;
  const int tx = tid & 15, ty = tid >> 4;

  __shared__ float Qs[TQ * 128];            // swizzled, 64 rows x 32 quads
  __shared__ float KVs[TK * 132];           // K swizzled (uses 4096 fl); V padded rows
  __shared__ unsigned short Ps[TQ * 36];    // bf16 P, row stride 36

  // stage Q once (swizzled)
  {
    const int qd = tid & 31, r0 = tid >> 5;
    #pragma unroll
    for (int s = 0; s < 8; ++s) {
      const int row = r0 + s * 8;
      const float4 v = *(const float4*)&Q[((size_t)b * NPOS + n0 + row) * ICH + qd * 4];
      *(float4*)&Qs[swz(row, qd) * 4] = v;
    }
  }

  float o_acc[4][8] = {};                   // rows n = ty*4+i, cols d = tx*8..+7
  float m_run[4], l_run[4];
  #pragma unroll
  for (int i = 0; i < 4; ++i) { m_run[i] = -1e30f; l_run[i] = 0.0f; }

  const int sq  = ty & 7;                   // Q swizzle group (row>>2 == ty)
  const int skz = (tx >> 1) & 7;            // K swizzle group for rows tx*2+j

  for (int m0 = 0; m0 < NPOS; m0 += TK) {
    __syncthreads();                        // prev PV done / Q staged
    {                                       // stage K tile, swizzled
      const int qd = tid & 31, r0 = tid >> 5;
      #pragma unroll
      for (int s = 0; s < 4; ++s) {
        const int row = r0 + s * 8;
        const float4 v = *(const float4*)&K[((size_t)b * NPOS + m0 + row) * ICH + qd * 4];
        *(float4*)&KVs[swz(row, qd) * 4] = v;
      }
    }
    __syncthreads();                        // K ready

    float s_[4][2] = {};                    // S rows ty*4+i, cols tx*2+j
    #pragma unroll 4
    for (int qd = 0; qd < 32; ++qd) {
      const int qq = (qd ^ sq)  * 4;
      const int kq = (qd ^ skz) * 4;
      float4 qv[4], kv[2];
      #pragma unroll
      for (int i = 0; i < 4; ++i) qv[i] = *(const float4*)&Qs[(ty * 4 + i) * 128 + qq];
      #pragma unroll
      for (int j = 0; j < 2; ++j) kv[j] = *(const float4*)&KVs[(tx * 2 + j) * 128 + kq];
      #pragma unroll
      for (int i = 0; i < 4; ++i)
        #pragma unroll
        for (int j = 0; j < 2; ++j)
          s_[i][j] += qv[i].x * kv[j].x + qv[i].y * kv[j].y
                    + qv[i].z * kv[j].z + qv[i].w * kv[j].w;
    }
    __syncthreads();                        // done reading K -> reuse buffer for V

    {                                       // stage V tile, padded rows (132 floats)
      const int qd = tid & 31, r0 = tid >> 5;
      #pragma unroll
      for (int s = 0; s < 4; ++s) {
        const int row = r0 + s * 8;
        const float4 v = *(const float4*)&V[((size_t)b * NPOS + m0 + row) * ICH + qd * 4];
        *(float4*)&KVs[row * 132 + qd * 4] = v;
      }
    }

    // online softmax update (16-lane butterfly over the row group)
    float alpha[4];
    #pragma unroll
    for (int i = 0; i < 4; ++i) {
      float mt = fmaxf(s_[i][0], s_[i][1]);
      #pragma unroll
      for (int off = 8; off >= 1; off >>= 1) mt = fmaxf(mt, __shfl_xor(mt, off, 64));
      const float mn = fmaxf(m_run[i], mt);
      alpha[i] = __expf(m_run[i] - mn);
      const float p0 = __expf(s_[i][0] - mn);
      const float p1 = __expf(s_[i][1] - mn);
      float ps = p0 + p1;
      #pragma unroll
      for (int off = 8; off >= 1; off >>= 1) ps += __shfl_xor(ps, off, 64);
      l_run[i] = l_run[i] * alpha[i] + ps;
      m_run[i] = mn;
      const unsigned int packed = (unsigned int)f2bf(p0) | ((unsigned int)f2bf(p1) << 16);
      *(unsigned int*)&Ps[(ty * 4 + i) * 36 + tx * 2] = packed;
    }
    __syncthreads();                        // V & P ready

    #pragma unroll
    for (int i = 0; i < 4; ++i)
      #pragma unroll
      for (int d = 0; d < 8; ++d) o_acc[i][d] *= alpha[i];

    #pragma unroll 2
    for (int mm = 0; mm < TK; mm += 4) {
      float p[4][4];
      #pragma unroll
      for (int i = 0; i < 4; ++i) {
        const uint2 raw = *(const uint2*)&Ps[(ty * 4 + i) * 36 + mm];
        p[i][0] = __uint_as_float(raw.x << 16);
        p[i][1] = __uint_as_float(raw.x & 0xffff0000u);
        p[i][2] = __uint_as_float(raw.y << 16);
        p[i][3] = __uint_as_float(raw.y & 0xffff0000u);
      }
      #pragma unroll
      for (int s = 0; s < 4; ++s) {
        const float4 v0 = *(const float4*)&KVs[(mm + s) * 132 + tx * 8];
        const float4 v1 = *(const float4*)&KVs[(mm + s) * 132 + tx * 8 + 4];
        #pragma unroll
        for (int i = 0; i < 4; ++i) {
          const float pv = p[i][s];
          o_acc[i][0] += pv * v0.x; o_acc[i][1] += pv * v0.y;
          o_acc[i][2] += pv * v0.z; o_acc[i][3] += pv * v0.w;
          o_acc[i][4] += pv * v1.x; o_acc[i][5] += pv * v1.y;
          o_acc[i][6] += pv * v1.z; o_acc[i][7] += pv * v1.w;
        }
      }
    }
  }

  #pragma unroll
  for (int i = 0; i < 4; ++i) {
    const float inv = 1.0f / l_run[i];
    const size_t base = ((size_t)b * NPOS + n0 + ty * 4 + i) * ICH + tx * 8;
    float4 v0, v1;
    v0.x = o_acc[i][0] * inv; v0.y = o_acc[i][1] * inv;
    v0.z = o_acc[i][2] * inv; v0.w = o_acc[i][3] * inv;
    v1.x = o_acc[i][4] * inv; v1.y = o_acc[i][5] * inv;
    v1.z = o_acc[i][6] * inv; v1.w = o_acc[i][7] * inv;
    *(float4*)&Y[base]     = v0;
    *(float4*)&Y[base + 4] = v1;
  }
}

// ---------------------------------------------------------------------------
// Kernel 3: z = Wz @ Y^T + x.  out[b][c][n] = sum_ic Wz[c][ic]*Y[b][n][ic] + x
// grid (N/64, C/64, B); block 256.
// ---------------------------------------------------------------------------
__global__ __launch_bounds__(256, 2)
void zres_kernel(const float* __restrict__ x,
                 const float* __restrict__ Wz,
                 const float* __restrict__ Y,
                 float* __restrict__ out) {
  const int n0 = blockIdx.x * 64;
  const int c0 = blockIdx.y * 64;
  const int b  = blockIdx.z;
  __shared__ float Yt[64][17];              // [n][kk]
  __shared__ float Wzt[64][17];             // [c][kk]
  const int tid = threadIdx.x;
  const int tx = tid & 15, ty = tid >> 4;
  float acc[4][4] = {};                     // rows c = ty*4+i, cols n = tx*4+j

  for (int ic0 = 0; ic0 < ICH; ic0 += 16) {
    {
      const int kk = tid & 15;
      const int rr = tid >> 4;
      #pragma unroll
      for (int p = 0; p < 4; ++p) {
        const int nn = rr + p * 16;
        Yt[nn][kk] = Y[((size_t)b * NPOS + n0 + nn) * ICH + ic0 + kk];
      }
      #pragma unroll
      for (int p = 0; p < 4; ++p) {
        const int cc = rr + p * 16;
        Wzt[cc][kk] = Wz[(size_t)(c0 + cc) * ICH + ic0 + kk];
      }
    }
    __syncthreads();
    #pragma unroll
    for (int kk = 0; kk < 16; ++kk) {
      float a_[4], b_[4];
      #pragma unroll
      for (int i = 0; i < 4; ++i) a_[i] = Wzt[ty * 4 + i][kk];
      #pragma unroll
      for (int j = 0; j < 4; ++j) b_[j] = Yt[tx * 4 + j][kk];
      #pragma unroll
      for (int i = 0; i < 4; ++i)
        #pragma unroll
        for (int j = 0; j < 4; ++j) acc[i][j] += a_[i] * b_[j];
    }
    __syncthreads();
  }
  #pragma unroll
  for (int i = 0; i < 4; ++i) {
    const size_t base = ((size_t)(b * CCH + c0 + ty * 4 + i)) * NPOS + n0 + tx * 4;
    const float4 xr = *(const float4*)&x[base];
    float4 v;
    v.x = acc[i][0] + xr.x; v.y = acc[i][1] + xr.y;
    v.z = acc[i][2] + xr.z; v.w = acc[i][3] + xr.w;
    *(float4*)&out[base] = v;
  }
}

// ---------------------------------------------------------------------------
extern "C" void kernel_launch(void* const* d_in, const int* in_sizes, int n_in,
                              void* d_out, int out_size, void* d_ws, size_t ws_size,
                              hipStream_t stream) {
  const float* x      = (const float*)d_in[0];
  const float* Wg     = (const float*)d_in[1];
  const float* Wtheta = (const float*)d_in[2];
  const float* Wphi   = (const float*)d_in[3];
  const float* Wz     = (const float*)d_in[4];
  float* ws  = (float*)d_ws;                 // needs 4*BNIC*4 = 51.4 MB
  float* out = (float*)d_out;
  float* Yb  = ws + 3 * BNIC;

  proj_kernel <<<dim3(NPOS / 64, 6, BB),      256, 0, stream>>>(x, Wtheta, Wphi, Wg, ws);
  flash_kernel<<<dim3(NPOS / TQ, BB),         256, 0, stream>>>(ws, Yb);
  zres_kernel <<<dim3(NPOS / 64, CCH / 64, BB), 256, 0, stream>>>(x, Wz, Yb, out);
}

// Round 3
// 497.735 us; speedup vs baseline: 4.2120x; 4.2120x over previous
//
#include <hip/hip_runtime.h>
#include <cstdint>

// SpacetimeNonLocalBlock: B=4, C=256, T*H*W=N=6272, IC=128.
// R2: fp16-MFMA flash attention (32x32x16_f16) — same structure as R1 (validated),
// fp16 instead of bf16 for Q/K/V/P to fix logit precision (bf16 2^-9 logit noise
// through a peaked softmax gave absmax 0.226 > 0.139; fp16 is 8x finer).
// ws: Qg f16 [B][N][128] | Kg f16 [B][N][128] | Vtg f16 [B][128][N] | Yt f32 [B][128][N]

#define BB   4
#define CCH  256
#define NPOS 6272
#define ICH  128
#define BNIC ((size_t)BB * NPOS * ICH)

typedef __attribute__((ext_vector_type(8)))  _Float16 h8v;  // 8 f16 (4 VGPR) MFMA frag
typedef __attribute__((ext_vector_type(2)))  _Float16 h2v;
typedef __attribute__((ext_vector_type(16))) float fx16;    // 32x32 accumulator

__device__ __forceinline__ unsigned short f2h(float f) {    // RNE fp32->fp16
  _Float16 h = (_Float16)f;
  return __builtin_bit_cast(unsigned short, h);
}
// pack two fp32 into (f16(lo) | f16(hi)<<16), single v_cvt_pkrtz_f16_f32.
__device__ __forceinline__ unsigned int pkh(float lo, float hi) {
  return __builtin_bit_cast(unsigned int, __builtin_amdgcn_cvt_pkrtz(lo, hi));
}

// ---------------------------------------------------------------------------
// proj_qk: Q/K [b][n][128] f16.  p = blockIdx.y>>1 (0:theta->Q, 1:phi->K)
// ---------------------------------------------------------------------------
__global__ __launch_bounds__(256, 2)
void proj_qk(const float* __restrict__ x,
             const float* __restrict__ Wtheta,
             const float* __restrict__ Wphi,
             unsigned short* __restrict__ Qg,
             unsigned short* __restrict__ Kg) {
  const int n0 = blockIdx.x * 64;
  const int p  = blockIdx.y >> 1;
  const int o_half = (blockIdx.y & 1) * 64;
  const int b  = blockIdx.z;
  const float* W = p ? Wphi : Wtheta;
  unsigned short* Out = p ? Kg : Qg;

  __shared__ float Xt[64][17];
  __shared__ float Wt[64][17];
  const int tid = threadIdx.x;
  const int tx = tid & 15, ty = tid >> 4;
  float acc[4][4] = {};

  for (int c0 = 0; c0 < CCH; c0 += 16) {
    {
      const int nn = tid & 63, k4 = tid >> 6;
      #pragma unroll
      for (int q = 0; q < 4; ++q) {
        const int kk = k4 + q * 4;
        Xt[nn][kk] = x[((size_t)(b * CCH + c0 + kk)) * NPOS + n0 + nn];
      }
      const int wk = tid & 15, wo = tid >> 4;
      #pragma unroll
      for (int q = 0; q < 4; ++q) {
        const int oo = wo + q * 16;
        Wt[oo][wk] = W[(size_t)(o_half + oo) * CCH + c0 + wk];
      }
    }
    __syncthreads();
    #pragma unroll
    for (int kk = 0; kk < 16; ++kk) {
      float a_[4], b_[4];
      #pragma unroll
      for (int i = 0; i < 4; ++i) a_[i] = Xt[ty * 4 + i][kk];
      #pragma unroll
      for (int j = 0; j < 4; ++j) b_[j] = Wt[tx * 4 + j][kk];
      #pragma unroll
      for (int i = 0; i < 4; ++i)
        #pragma unroll
        for (int j = 0; j < 4; ++j) acc[i][j] += a_[i] * b_[j];
    }
    __syncthreads();
  }
  #pragma unroll
  for (int i = 0; i < 4; ++i) {
    ushort4 v;
    v.x = f2h(acc[i][0]); v.y = f2h(acc[i][1]);
    v.z = f2h(acc[i][2]); v.w = f2h(acc[i][3]);
    *(ushort4*)&Out[((size_t)b * NPOS + n0 + ty * 4 + i) * ICH + o_half + tx * 4] = v;
  }
}

// ---------------------------------------------------------------------------
// proj_v: V^T [b][128][N] f16 (rows=o, cols=n).
// ---------------------------------------------------------------------------
__global__ __launch_bounds__(256, 2)
void proj_v(const float* __restrict__ x,
            const float* __restrict__ Wg,
            unsigned short* __restrict__ Vtg) {
  const int n0 = blockIdx.x * 64;
  const int o_half = blockIdx.y * 64;
  const int b  = blockIdx.z;
  __shared__ float Xt[64][17];
  __shared__ float Wt[64][17];
  const int tid = threadIdx.x;
  const int tx = tid & 15, ty = tid >> 4;
  float acc[4][4] = {};   // rows o = ty*4+i, cols n = tx*4+j

  for (int c0 = 0; c0 < CCH; c0 += 16) {
    {
      const int nn = tid & 63, k4 = tid >> 6;
      #pragma unroll
      for (int q = 0; q < 4; ++q) {
        const int kk = k4 + q * 4;
        Xt[nn][kk] = x[((size_t)(b * CCH + c0 + kk)) * NPOS + n0 + nn];
      }
      const int wk = tid & 15, wo = tid >> 4;
      #pragma unroll
      for (int q = 0; q < 4; ++q) {
        const int oo = wo + q * 16;
        Wt[oo][wk] = Wg[(size_t)(o_half + oo) * CCH + c0 + wk];
      }
    }
    __syncthreads();
    #pragma unroll
    for (int kk = 0; kk < 16; ++kk) {
      float a_[4], b_[4];
      #pragma unroll
      for (int i = 0; i < 4; ++i) a_[i] = Wt[ty * 4 + i][kk];
      #pragma unroll
      for (int j = 0; j < 4; ++j) b_[j] = Xt[tx * 4 + j][kk];
      #pragma unroll
      for (int i = 0; i < 4; ++i)
        #pragma unroll
        for (int j = 0; j < 4; ++j) acc[i][j] += a_[i] * b_[j];
    }
    __syncthreads();
  }
  #pragma unroll
  for (int i = 0; i < 4; ++i) {
    ushort4 v;
    v.x = f2h(acc[i][0]); v.y = f2h(acc[i][1]);
    v.z = f2h(acc[i][2]); v.w = f2h(acc[i][3]);
    *(ushort4*)&Vtg[((size_t)b * ICH + o_half + ty * 4 + i) * NPOS + n0 + tx * 4] = v;
  }
}

// ---------------------------------------------------------------------------
// flash2: Y^T[b][d][n]. grid (49, B), 4 waves; wave w owns q cols n0+32w..+31.
// S^T = K.Q^T (A=K LDS, B=Q regs); PV: O^T = V^T.P^T (A=V^T LDS, B=P via shfl).
// LDS 64 KB: K[2][64x128], V^T[2][128x64], 16B-chunk XOR swizzle, dbuffered.
// ---------------------------------------------------------------------------
#define TKF 64
#define NIT (NPOS / TKF)   // 98

__global__ __launch_bounds__(256, 1)
void flash2(const unsigned short* __restrict__ Qg,
            const unsigned short* __restrict__ Kg,
            const unsigned short* __restrict__ Vtg,
            float* __restrict__ Yt) {
  __shared__ unsigned short Ks[2][TKF * 128];   // [k-row][ch], 16 chunks/row
  __shared__ unsigned short Vs[2][128 * TKF];   // [d-row][k],  8 chunks/row

  const int b   = blockIdx.y;
  const int n0  = blockIdx.x * 128;
  const int tid = threadIdx.x;
  const int lane = tid & 63, wv = tid >> 6;
  const int qlane = lane & 31, g = lane >> 5;
  const int swz = qlane & 7;

  // Q fragments in registers for the whole kernel (B-operand: B[ch][q])
  h8v qf[8];
  {
    const size_t qbase = ((size_t)b * NPOS + n0 + 32 * wv + qlane) * ICH;
    #pragma unroll
    for (int cs = 0; cs < 8; ++cs)
      qf[cs] = *(const h8v*)&Qg[qbase + cs * 16 + g * 8];
  }

  // prologue: stage tile 0 into buffer 0
  {
    #pragma unroll
    for (int s4 = 0; s4 < 4; ++s4) {
      const int kr = 16 * wv + 4 * s4 + (lane >> 4);
      const int kc = lane & 15;
      uint4 v = *(const uint4*)&Kg[((size_t)b * NPOS + kr) * ICH + kc * 8];
      *(uint4*)&Ks[0][kr * 128 + ((kc ^ (kr & 7))) * 8] = v;
      const int dr = 32 * wv + 8 * s4 + (lane >> 3);
      const int dc = lane & 7;
      uint4 w = *(const uint4*)&Vtg[((size_t)b * ICH + dr) * NPOS + dc * 8];
      *(uint4*)&Vs[0][dr * TKF + ((dc ^ (dr & 7))) * 8] = w;
    }
  }
  __syncthreads();

  float m_run = -1e30f, l_run = 0.0f;
  fx16 accO[4];
  #pragma unroll
  for (int mt = 0; mt < 4; ++mt) accO[mt] = (fx16)(0.0f);

  uint4 stgK[4], stgV[4];

  for (int it = 0; it < NIT; ++it) {
    const int cur = it & 1;
    const bool pre = (it + 1 < NIT);
    if (pre) {  // global loads for next tile; writes deferred past compute
      const int k0n = (it + 1) * TKF;
      #pragma unroll
      for (int s4 = 0; s4 < 4; ++s4) {
        const int kr = 16 * wv + 4 * s4 + (lane >> 4);
        stgK[s4] = *(const uint4*)&Kg[((size_t)b * NPOS + k0n + kr) * ICH + (lane & 15) * 8];
        const int dr = 32 * wv + 8 * s4 + (lane >> 3);
        stgV[s4] = *(const uint4*)&Vtg[((size_t)b * ICH + dr) * NPOS + k0n + (lane & 7) * 8];
      }
    }

    // ---- S^T = K . Q^T : D[k][q], tiles mt = k 32-halves ----
    fx16 accS[2];
    accS[0] = (fx16)(0.0f); accS[1] = (fx16)(0.0f);
    #pragma unroll
    for (int cs = 0; cs < 8; ++cs) {
      #pragma unroll
      for (int mt = 0; mt < 2; ++mt) {
        const h8v aK = *(const h8v*)&Ks[cur][(32 * mt + qlane) * 128 + (((2 * cs + g) ^ swz)) * 8];
        accS[mt] = __builtin_amdgcn_mfma_f32_32x32x16_f16(aK, qf[cs], accS[mt], 0, 0, 0);
      }
    }

    // ---- online softmax (per lane: one q column; xor-32 merges k halves) ----
    float mx = accS[0][0];
    #pragma unroll
    for (int r = 1; r < 16; ++r) mx = fmaxf(mx, accS[0][r]);
    #pragma unroll
    for (int r = 0; r < 16; ++r) mx = fmaxf(mx, accS[1][r]);
    mx = fmaxf(mx, __shfl_xor(mx, 32));
    const float mn = fmaxf(m_run, mx);
    const float alpha = __expf(m_run - mn);
    float lsum = 0.0f;
    unsigned int pk[2][4][2];
    #pragma unroll
    for (int mt = 0; mt < 2; ++mt)
      #pragma unroll
      for (int u = 0; u < 4; ++u) {
        const float p0 = __expf(accS[mt][4 * u + 0] - mn);
        const float p1 = __expf(accS[mt][4 * u + 1] - mn);
        const float p2 = __expf(accS[mt][4 * u + 2] - mn);
        const float p3 = __expf(accS[mt][4 * u + 3] - mn);
        lsum += (p0 + p1) + (p2 + p3);
        pk[mt][u][0] = pkh(p0, p1);
        pk[mt][u][1] = pkh(p2, p3);
      }
    lsum += __shfl_xor(lsum, 32);
    l_run = l_run * alpha + lsum;
    m_run = mn;
    #pragma unroll
    for (int mt = 0; mt < 4; ++mt)
      #pragma unroll
      for (int r = 0; r < 16; ++r) accO[mt][r] *= alpha;

    // ---- PV: O^T += V^T . P^T ----
    #pragma unroll
    for (int s = 0; s < 4; ++s) {
      const int mtp = s >> 1, sb = s & 1;
      const unsigned int v0 = pk[mtp][2 * sb + (g ^ 1)][0];
      const unsigned int v1 = pk[mtp][2 * sb + (g ^ 1)][1];
      const unsigned int t0 = __shfl_xor(v0, 32);
      const unsigned int t1 = __shfl_xor(v1, 32);
      union { unsigned int u[4]; h8v v; } bP;
      bP.u[0] = g ? t0 : pk[mtp][2 * sb][0];
      bP.u[1] = g ? t1 : pk[mtp][2 * sb][1];
      bP.u[2] = g ? pk[mtp][2 * sb + 1][0] : t0;
      bP.u[3] = g ? pk[mtp][2 * sb + 1][1] : t1;
      #pragma unroll
      for (int mt = 0; mt < 4; ++mt) {
        const h8v aV = *(const h8v*)&Vs[cur][(32 * mt + qlane) * TKF + (((2 * s + g) ^ swz)) * 8];
        accO[mt] = __builtin_amdgcn_mfma_f32_32x32x16_f16(aV, bP.v, accO[mt], 0, 0, 0);
      }
    }

    if (pre) {  // commit staged tile to the other buffer
      const int nb = cur ^ 1;
      #pragma unroll
      for (int s4 = 0; s4 < 4; ++s4) {
        const int kr = 16 * wv + 4 * s4 + (lane >> 4);
        *(uint4*)&Ks[nb][kr * 128 + (((lane & 15) ^ (kr & 7))) * 8] = stgK[s4];
        const int dr = 32 * wv + 8 * s4 + (lane >> 3);
        *(uint4*)&Vs[nb][dr * TKF + (((lane & 7) ^ (dr & 7))) * 8] = stgV[s4];
      }
    }
    __syncthreads();
  }

  // epilogue: Y^T[b][d][n] = O^T / l
  const float inv = 1.0f / l_run;
  const int ncol = n0 + 32 * wv + qlane;
  #pragma unroll
  for (int mt = 0; mt < 4; ++mt)
    #pragma unroll
    for (int r = 0; r < 16; ++r) {
      const int d = 32 * mt + (r & 3) + 8 * (r >> 2) + 4 * g;
      Yt[((size_t)b * ICH + d) * NPOS + ncol] = accO[mt][r] * inv;
    }
}

// ---------------------------------------------------------------------------
// zres: out[b][c][n] = sum_ic Wz[c][ic] * Y^T[b][ic][n] + x
// ---------------------------------------------------------------------------
__global__ __launch_bounds__(256, 2)
void zres_kernel(const float* __restrict__ x,
                 const float* __restrict__ Wz,
                 const float* __restrict__ Yt,
                 float* __restrict__ out) {
  const int n0 = blockIdx.x * 64;
  const int c0 = blockIdx.y * 64;
  const int b  = blockIdx.z;
  __shared__ float Yts[64][17];              // [n][kk(ic)]
  __shared__ float Wzt[64][17];              // [c][kk]
  const int tid = threadIdx.x;
  const int tx = tid & 15, ty = tid >> 4;
  float acc[4][4] = {};                      // rows c = ty*4+i, cols n = tx*4+j

  for (int ic0 = 0; ic0 < ICH; ic0 += 16) {
    {
      const int nn = tid & 63, k4 = tid >> 6;
      #pragma unroll
      for (int q = 0; q < 4; ++q) {
        const int kk = k4 + q * 4;
        Yts[nn][kk] = Yt[((size_t)b * ICH + ic0 + kk) * NPOS + n0 + nn];
      }
      const int kk = tid & 15, rr = tid >> 4;
      #pragma unroll
      for (int q = 0; q < 4; ++q) {
        const int cc = rr + q * 16;
        Wzt[cc][kk] = Wz[(size_t)(c0 + cc) * ICH + ic0 + kk];
      }
    }
    __syncthreads();
    #pragma unroll
    for (int kk = 0; kk < 16; ++kk) {
      float a_[4], b_[4];
      #pragma unroll
      for (int i = 0; i < 4; ++i) a_[i] = Wzt[ty * 4 + i][kk];
      #pragma unroll
      for (int j = 0; j < 4; ++j) b_[j] = Yts[tx * 4 + j][kk];
      #pragma unroll
      for (int i = 0; i < 4; ++i)
        #pragma unroll
        for (int j = 0; j < 4; ++j) acc[i][j] += a_[i] * b_[j];
    }
    __syncthreads();
  }
  #pragma unroll
  for (int i = 0; i < 4; ++i) {
    const size_t base = ((size_t)(b * CCH + c0 + ty * 4 + i)) * NPOS + n0 + tx * 4;
    const float4 xr = *(const float4*)&x[base];
    float4 v;
    v.x = acc[i][0] + xr.x; v.y = acc[i][1] + xr.y;
    v.z = acc[i][2] + xr.z; v.w = acc[i][3] + xr.w;
    *(float4*)&out[base] = v;
  }
}

// ---------------------------------------------------------------------------
extern "C" void kernel_launch(void* const* d_in, const int* in_sizes, int n_in,
                              void* d_out, int out_size, void* d_ws, size_t ws_size,
                              hipStream_t stream) {
  const float* x      = (const float*)d_in[0];
  const float* Wg     = (const float*)d_in[1];
  const float* Wtheta = (const float*)d_in[2];
  const float* Wphi   = (const float*)d_in[3];
  const float* Wz     = (const float*)d_in[4];
  float* out = (float*)d_out;

  unsigned short* Qg  = (unsigned short*)d_ws;
  unsigned short* Kg  = Qg + BNIC;
  unsigned short* Vtg = Kg + BNIC;
  float*          Yt  = (float*)(Vtg + BNIC);

  proj_qk<<<dim3(NPOS / 64, 4, BB), 256, 0, stream>>>(x, Wtheta, Wphi, Qg, Kg);
  proj_v <<<dim3(NPOS / 64, 2, BB), 256, 0, stream>>>(x, Wg, Vtg);
  flash2 <<<dim3(NPOS / 128, BB),   256, 0, stream>>>(Qg, Kg, Vtg, Yt);
  zres_kernel<<<dim3(NPOS / 64, CCH / 64, BB), 256, 0, stream>>>(x, Wz, Yt, out);
}